// Round 13
// baseline (138.271 us; speedup 1.0000x reference)
//
#include <hip/hip_runtime.h>
#include <hip/hip_bf16.h>
#include <math.h>

#define H 120
#define W 216
#define C 256
#define NPIX (H*W)
#define PATCH 13
#define PP 169
#define RAD 6
#define TOPKN 36
#define OBJ 11
#define MD 4
#define CW 344   // padded corr row stride (338 -> 344)

typedef unsigned short ushort;
typedef unsigned int   uint;
typedef __attribute__((ext_vector_type(8))) __bf16 bf16x8;
typedef __attribute__((ext_vector_type(4))) float   f32x4;

#define PLANE_B ((size_t)NPIX * 512)   // bytes per hi/lo plane of a transposed tensor

// corr tile geometry
#define YT 8                    // y rows per block
#define RT 20                   // staged fm rows = YT + 12
#define XT 16                   // x cols per block (one M tile)
#define UW 32                   // u window = XT + 16
#define PXS 128                 // staged px stride: 2 planes x 64B, XOR-swizzled reads
#define ROWS (UW * PXS)         // 4096 B per staged row
#define BUFB (RT * ROWS)        // 81920 B per buffer
#define NXT 14                  // ceil(216/16)
#define NYT 15                  // 120/8
#define NWG (NXT * 2 * NYT)     // 420 blocks

__device__ inline ushort f2bf_rne(float x) {
  uint u = __float_as_uint(x);
  uint r = (u + 0x7FFFu + ((u >> 16) & 1u)) >> 16;
  return (ushort)r;
}
__device__ inline float bf2f(ushort h) { return __uint_as_float(((uint)h) << 16); }

// ---------------- kernel 0: transpose + hi/lo bf16 split ----------------
__global__ __launch_bounds__(256) void k_prep(const float* __restrict__ fq,
                      const float* __restrict__ fm0, const float* __restrict__ fm1,
                      char* fqt, char* fm0t, char* fm1t) {
  const float* src = (blockIdx.z == 0) ? fq : (blockIdx.z == 1) ? fm0 : fm1;
  char* dst = (blockIdx.z == 0) ? fqt : (blockIdx.z == 1) ? fm0t : fm1t;

  const int p0 = blockIdx.x * 64;
  const int c0 = blockIdx.y * 64;
  const int tid = threadIdx.x;

  __shared__ float ts[64 * 65];
  {
    int p = tid & 63, cl = tid >> 6;
    #pragma unroll
    for (int jj = 0; jj < 16; ++jj) {
      int c = 4 * jj + cl;
      ts[c * 65 + p] = src[(size_t)(c0 + c) * NPIX + p0 + p];
    }
  }
  __syncthreads();
  {
    int pl = tid >> 2, sub = tid & 3;
    ushort hb[16], lb[16];
    #pragma unroll
    for (int i = 0; i < 16; ++i) {
      float x = ts[(sub * 16 + i) * 65 + pl];
      ushort h = f2bf_rne(x);
      hb[i] = h;
      lb[i] = f2bf_rne(x - bf2f(h));
    }
    size_t off = (size_t)(p0 + pl) * 512 + (size_t)c0 * 2 + sub * 32;
    *(uint4*)(dst + off)            = ((uint4*)hb)[0];
    *(uint4*)(dst + off + 16)       = ((uint4*)hb)[1];
    *(uint4*)(dst + PLANE_B + off)      = ((uint4*)lb)[0];
    *(uint4*)(dst + PLANE_B + off + 16) = ((uint4*)lb)[1];
  }
}

// ---------------- kernel 1: mask downsample (::4,::4) ----------------
__global__ void k_downsample(const float* __restrict__ m0, const float* __restrict__ m1,
                             float* __restrict__ mds) {
  int i = blockIdx.x * 256 + threadIdx.x;
  const int total = 2 * OBJ * NPIX;
  if (i >= total) return;
  int fo = i / NPIX;
  int pix = i - fo * NPIX;
  int f = fo / OBJ, o = fo - f * OBJ;
  int y = pix / W, x = pix - y * W;
  const float* src = f ? m1 : m0;
  mds[i] = src[(size_t)o * (H*MD) * (W*MD) + (size_t)(MD*y) * (W*MD) + MD*x];
}

// ---------------- kernel 2 (MFMA, y-paired waves: wave = (y-pair, nt)) ----------------
// LDS-read volume is the binding resource (54% pipe util incl. tail). One wave owns TWO
// adjacent y rows: the 14 staged rows y0-6..y0+7 are read ONCE and feed y0 (di=ri) and
// y0+1 (di=ri-1) -> 28 reads/kc/wave vs 52 for two single-y waves. acc[2][13]=104 AGPR,
// 2 waves/SIMD. Staging/swizzle/dbuf identical to R12; per-acc MFMA chain identical
// (kc asc x [AhBh, AhBl, AlBh]) -> corr bit-identical.
__global__ __launch_bounds__(512, 2) void k_corr_mfma(const char* __restrict__ fqt,
                        const char* __restrict__ fm0t, const char* __restrict__ fm1t,
                        float* __restrict__ corr) {
  int b = blockIdx.x;
  int xcd = b & 7;
  int wgid = ((xcd < 4) ? xcd * 53 : 4 * 53 + (xcd - 4) * 52) + (b >> 3);
  int yt   = wgid % NYT;
  int rest = wgid / NYT;
  int f    = rest & 1;
  int xt   = rest >> 1;

  const int y0 = yt * YT;
  const int X0 = xt * XT;
  const int tid  = threadIdx.x;
  const int wv   = tid >> 6;           // wave id 0..7
  const int p    = wv >> 1;            // y-pair 0..3
  const int nt   = wv & 1;             // u group
  const int lane = tid & 63;
  const int l15  = lane & 15, l4 = lane >> 4;
  const int ya   = y0 + 2 * p;         // wave's first y (ya, ya+1 both in [0,120))

  const char* frame = f ? fm1t : fm0t;

  __shared__ __align__(16) char bsm[2 * BUFB];   // 163840 B

  // ---- staging sources: 5120 granules = 512 threads x 10; linear dest, inverse-swz source
  const char* gsrc[10];
  #pragma unroll
  for (int i = 0; i < 10; ++i) {
    int gdest = wv * 640 + i * 64 + lane;
    int ri  = gdest >> 8;          // 0..19
    int rem = gdest & 255;
    int px  = rem >> 3;            // 0..31
    int pqp = rem & 7;
    int pqs = pqp ^ (px & 7);      // source (p,q) granule (rule #21 inverse swizzle)
    int pp  = pqs >> 2, q = pqs & 3;
    int r = y0 - 6 + ri;  r = (r < 0) ? 0 : (r >= H ? H - 1 : r);
    int u = X0 - 8 + px;  u = (u < 0) ? 0 : (u >= W ? W - 1 : u);
    gsrc[i] = frame + (size_t)pp * PLANE_B + (size_t)(r * W + u) * 512 + q * 16;
  }

  // A bases for the two y rows (x = X0 + l15, octet l4)
  int xA = X0 + l15;
  const char* pa0 = fqt + (size_t)(ya * W + (xA < W ? xA : W - 1)) * 512 + l4 * 16;
  const char* pa1 = pa0 + (size_t)W * 512;

  // B read offsets (within a staged row), swizzled to match the source permutation
  const int pxn = 16 * nt + l15;
  const uint sw  = (uint)((l15 & 7) << 4);
  const uint bh_off = (uint)((pxn * PXS +      l4 * 16) ^ sw);
  const uint bl_off = (uint)((pxn * PXS + 64 + l4 * 16) ^ sw);

  int u0 = X0 + 16 * nt + l15 - 8;
  bool uok = (u0 >= 0) && (u0 < W);

  f32x4 acc0[13], acc1[13];
  #pragma unroll
  for (int di = 0; di < 13; ++di) {
    acc0[di] = (f32x4){0.f, 0.f, 0.f, 0.f};
    acc1[di] = (f32x4){0.f, 0.f, 0.f, 0.f};
  }

  auto STAGE = [&](int buf, int kc) {
    #pragma unroll
    for (int i = 0; i < 10; ++i)
      __builtin_amdgcn_global_load_lds(
        (const __attribute__((address_space(1))) void*)(gsrc[i] + kc * 64),
        (__attribute__((address_space(3))) void*)(bsm + buf * BUFB + wv * 10240 + i * 1024),
        16, 0, 0);
  };

  STAGE(0, 0);
  uint4 aC0h = *(const uint4*)(pa0);
  uint4 aC0l = *(const uint4*)(pa0 + PLANE_B);
  uint4 aC1h = *(const uint4*)(pa1);
  uint4 aC1l = *(const uint4*)(pa1 + PLANE_B);
  uint4 aN0h, aN0l, aN1h, aN1l;
  __syncthreads();   // buf0 ready

  #pragma unroll
  for (int kc = 0; kc < 8; ++kc) {
    if (kc < 7) {
      STAGE((kc + 1) & 1, kc + 1);             // flies under this kc's compute
      aN0h = *(const uint4*)(pa0 + (kc + 1) * 64);
      aN0l = *(const uint4*)(pa0 + PLANE_B + (kc + 1) * 64);
      aN1h = *(const uint4*)(pa1 + (kc + 1) * 64);
      aN1l = *(const uint4*)(pa1 + PLANE_B + (kc + 1) * 64);
    }
    const char* bb = bsm + (kc & 1) * BUFB;
    bf16x8 A0h = __builtin_bit_cast(bf16x8, aC0h);
    bf16x8 A0l = __builtin_bit_cast(bf16x8, aC0l);
    bf16x8 A1h = __builtin_bit_cast(bf16x8, aC1h);
    bf16x8 A1l = __builtin_bit_cast(bf16x8, aC1l);

    // 14 staged rows feed both y's: row = ya + ri - 6; di0 = ri (y=ya), di1 = ri-1 (y=ya+1)
    #pragma unroll
    for (int ri = 0; ri < 14; ++ri) {
      int row = ya + ri - RAD;
      if (row >= 0 && row < H) {               // wave-uniform
        const char* rb = bb + (2 * p + ri) * ROWS;
        bf16x8 Bhv = *(const bf16x8*)(rb + bh_off);
        bf16x8 Blv = *(const bf16x8*)(rb + bl_off);
        if (ri <= 12) {
          acc0[ri] = __builtin_amdgcn_mfma_f32_16x16x32_bf16(A0h, Bhv, acc0[ri], 0, 0, 0);
          acc0[ri] = __builtin_amdgcn_mfma_f32_16x16x32_bf16(A0h, Blv, acc0[ri], 0, 0, 0);
          acc0[ri] = __builtin_amdgcn_mfma_f32_16x16x32_bf16(A0l, Bhv, acc0[ri], 0, 0, 0);
        }
        if (ri >= 1) {
          acc1[ri-1] = __builtin_amdgcn_mfma_f32_16x16x32_bf16(A1h, Bhv, acc1[ri-1], 0, 0, 0);
          acc1[ri-1] = __builtin_amdgcn_mfma_f32_16x16x32_bf16(A1h, Blv, acc1[ri-1], 0, 0, 0);
          acc1[ri-1] = __builtin_amdgcn_mfma_f32_16x16x32_bf16(A1l, Bhv, acc1[ri-1], 0, 0, 0);
        }
      }
    }
    aC0h = aN0h; aC0l = aN0l; aC1h = aN1h; aC1l = aN1l;   // static rotate
    __syncthreads();                           // vmcnt drain (staging mostly landed) + barrier
  }

  // ---- band extraction for both y rows: dj = 16nt + l15 - m - 2
  float* cb0 = corr + (size_t)(ya * W) * CW + f * PP;
  float* cb1 = cb0 + (size_t)W * CW;
  #pragma unroll
  for (int di = 0; di < 13; ++di) {
    #pragma unroll
    for (int j = 0; j < 4; ++j) {
      int m  = l4 * 4 + j;
      int x  = X0 + m;
      int dj = 16 * nt + l15 - m - 2;
      if (x < W && dj >= 0 && dj < PATCH) {
        cb0[(size_t)x * CW + di * PATCH + dj] = uok ? acc0[di][j] * 0.0625f : 0.f;
        cb1[(size_t)x * CW + di * PATCH + dj] = uok ? acc1[di][j] * 0.0625f : 0.f;
      }
    }
  }
}

// ---------------- kernel 2 fallback (VALU, R2-validated) ----------------
__global__ __launch_bounds__(64) void k_corr_valu(const float* __restrict__ fq,
                       const float* __restrict__ fm0, const float* __restrict__ fm1,
                       float* __restrict__ corr) {
  int b = blockIdx.x;
  int lb = (b & 7) * 390 + (b >> 3);
  int y   = lb / 26;
  int r26 = lb - y * 26;
  int f   = r26 / 13;
  int di  = r26 - f * 13;
  const int tid = threadIdx.x;
  const int xg  = tid;
  const int r   = y + di - RAD;

  float* corr_base = corr + (size_t)(y * W) * CW + (f * PP + di * PATCH);

  if (r < 0 || r >= H) {
    if (xg < 54) {
      float* cp = corr_base + (size_t)(4 * xg) * CW;
      #pragma unroll
      for (int sub = 0; sub < 4; ++sub) {
        #pragma unroll
        for (int dj = 0; dj < PATCH; ++dj) cp[(size_t)sub * CW + dj] = 0.f;
      }
    }
    return;
  }

  const float* fm = f ? fm1 : fm0;
  __shared__ float fm_s[4 * 232];

  const float* pf[4];
  int  ldsoff[4];
  bool sval[4], mval[4];
  #pragma unroll
  for (int s = 0; s < 4; ++s) {
    int i = tid + 64 * s;
    sval[s] = (i < 232);
    int ii = sval[s] ? i : 0;
    int ch = ii / 58;
    int m  = ii - ch * 58;
    int x  = 4 * m - 8;
    mval[s] = sval[s] && (m >= 2) && (m <= 55);
    ldsoff[s] = ch * 232 + 4 * m;
    pf[s] = fm + (size_t)ch * NPIX + (size_t)r * W + (mval[s] ? x : 0);
  }

  const float* pq = fq + (size_t)y * W + 4 * ((xg < 54) ? xg : 0);

  float4 acc[PATCH];
  #pragma unroll
  for (int d = 0; d < PATCH; ++d) acc[d] = make_float4(0.f, 0.f, 0.f, 0.f);

  for (int c0 = 0; c0 < C; c0 += 4) {
    #pragma unroll
    for (int s = 0; s < 4; ++s) {
      if (sval[s]) {
        float4 v = make_float4(0.f, 0.f, 0.f, 0.f);
        if (mval[s]) v = *(const float4*)(pf[s]);
        *(float4*)&fm_s[ldsoff[s]] = v;
        pf[s] += 4 * (size_t)NPIX;
      }
    }
    __syncthreads();
    if (xg < 54) {
      #pragma unroll
      for (int ch = 0; ch < 4; ++ch) {
        float4 q4 = *(const float4*)(pq + (size_t)ch * NPIX);
        float rv[20];
        #pragma unroll
        for (int qq = 0; qq < 5; ++qq) {
          float4 t4 = *(const float4*)&fm_s[ch * 232 + 4 * xg + 4 * qq];
          rv[4*qq+0] = t4.x; rv[4*qq+1] = t4.y; rv[4*qq+2] = t4.z; rv[4*qq+3] = t4.w;
        }
        #pragma unroll
        for (int dj = 0; dj < PATCH; ++dj) {
          acc[dj].x += q4.x * rv[dj + 2];
          acc[dj].y += q4.y * rv[dj + 3];
          acc[dj].z += q4.z * rv[dj + 4];
          acc[dj].w += q4.w * rv[dj + 5];
        }
      }
      pq += 4 * (size_t)NPIX;
    }
    __syncthreads();
  }

  if (xg < 54) {
    float* cp = corr_base + (size_t)(4 * xg) * CW;
    #pragma unroll
    for (int dj = 0; dj < PATCH; ++dj) {
      cp[dj]                  = acc[dj].x * 0.0625f;
      cp[(size_t)1 * CW + dj] = acc[dj].y * 0.0625f;
      cp[(size_t)2 * CW + dj] = acc[dj].z * 0.0625f;
      cp[(size_t)3 * CW + dj] = acc[dj].w * 0.0625f;
    }
  }
}

// ---------------- kernel 3: per-pixel top-36 via ballot-count rank select (R8-validated) ----------------
__global__ __launch_bounds__(256) void k_topk(const float* __restrict__ corr,
                       const float* __restrict__ mds, float* __restrict__ out) {
  int wid = (blockIdx.x * 256 + threadIdx.x) >> 6;
  int lane = threadIdx.x & 63;
  if (wid >= NPIX) return;
  const float* cr = corr + (size_t)wid * CW;

  float v[6]; uint ui[6];
  #pragma unroll
  for (int s = 0; s < 6; ++s) {
    int idx = lane + 64 * s;
    bool ok = idx < 2 * PP;
    float f = ok ? cr[idx] : 0.f;
    v[s] = f;
    uint bb = __float_as_uint(f);
    uint u = bb ^ (uint)(((int)bb >> 31) | 0x80000000);
    ui[s] = ok ? u : 0u;
  }

  uint blo = 0u, bhi = 0xFFFFFFFFu;
  for (int it = 0; it < 32; ++it) {
    uint mid = blo + ((bhi - blo) >> 1);
    int c = 0;
    #pragma unroll
    for (int s = 0; s < 6; ++s)
      c += __popcll(__ballot(ui[s] > mid));
    if (c <= 35) bhi = mid; else blo = mid + 1;
  }
  const uint x0 = blo;

  int c_gt = 0;
  #pragma unroll
  for (int s = 0; s < 6; ++s) c_gt += __popcll(__ballot(ui[s] > x0));
  const int need = 36 - c_gt;

  uint tb = (x0 & 0x80000000u) ? (x0 ^ 0x80000000u) : ~x0;
  const float tf = __uint_as_float(tb);

  float w[6];
  float zp = 0.f;
  int prior = 0;
  #pragma unroll
  for (int s = 0; s < 6; ++s) {
    unsigned long long tie = __ballot(ui[s] == x0);
    uint below = __builtin_amdgcn_mbcnt_hi((uint)(tie >> 32),
                  __builtin_amdgcn_mbcnt_lo((uint)tie, 0u));
    bool acc = (ui[s] > x0) || ((ui[s] == x0) && ((prior + (int)below) < need));
    prior += __popcll(tie);
    w[s] = acc ? __expf(v[s] - tf) : 0.f;
    zp += w[s];
  }
  float Z = zp;
  #pragma unroll
  for (int off = 32; off >= 1; off >>= 1) Z += __shfl_xor(Z, off, 64);

  int y = wid / W, x = wid - (wid / W) * W;
  float no[OBJ];
  #pragma unroll
  for (int o = 0; o < OBJ; ++o) no[o] = 0.f;
  #pragma unroll
  for (int s = 0; s < 6; ++s) {
    if (w[s] > 0.f) {
      int idx = lane + 64 * s;
      int ff = idx >= PP;
      int r = idx - ff * PP;
      int di = r / PATCH, dj = r - (r / PATCH) * PATCH;
      int yy = y + di - RAD, xx = x + dj - RAD;
      if (yy >= 0 && yy < H && xx >= 0 && xx < W) {
        const float* mb = mds + ((size_t)ff * OBJ) * NPIX + yy * W + xx;
        #pragma unroll
        for (int o = 0; o < OBJ; ++o) no[o] += w[s] * mb[(size_t)o * NPIX];
      }
    }
  }
  float inv = 1.f / Z;
  #pragma unroll
  for (int o = 0; o < OBJ; ++o) {
    float pr = no[o];
    #pragma unroll
    for (int off = 32; off >= 1; off >>= 1) pr += __shfl_xor(pr, off, 64);
    if (lane == 0) out[(size_t)o * NPIX + wid] = pr * inv;
  }
}

extern "C" void kernel_launch(void* const* d_in, const int* in_sizes, int n_in,
                              void* d_out, int out_size, void* d_ws, size_t ws_size,
                              hipStream_t stream) {
  const float* fq  = (const float*)d_in[0];
  const float* fm0 = (const float*)d_in[1];
  const float* fm1 = (const float*)d_in[2];
  const float* m0  = (const float*)d_in[3];
  const float* m1  = (const float*)d_in[4];
  float* out = (float*)d_out;

  char* ws = (char*)d_ws;
  size_t off = 0;
  auto alloc = [&](size_t sz) { size_t o = off; off = (off + sz + 1023) & ~(size_t)1023; return o; };

  size_t mds_o  = alloc((size_t)2 * OBJ * NPIX * sizeof(float));
  size_t corr_o = alloc((size_t)NPIX * CW * sizeof(float));
  size_t fqt_o  = alloc(2 * PLANE_B);
  size_t fm0t_o = alloc(2 * PLANE_B);
  size_t fm1t_o = alloc(2 * PLANE_B);
  size_t needed = off;

  float* mds  = (float*)(ws + mds_o);
  float* corr = (float*)(ws + corr_o);

  k_downsample<<<(2 * OBJ * NPIX + 255) / 256, 256, 0, stream>>>(m0, m1, mds);

  if (ws_size >= needed) {
    char* fqt  = ws + fqt_o;
    char* fm0t = ws + fm0t_o;
    char* fm1t = ws + fm1t_o;
    dim3 gp(405, 4, 3);
    k_prep<<<gp, 256, 0, stream>>>(fq, fm0, fm1, fqt, fm0t, fm1t);
    k_corr_mfma<<<NWG, 512, 0, stream>>>(fqt, fm0t, fm1t, corr);
  } else {
    k_corr_valu<<<120 * 26, 64, 0, stream>>>(fq, fm0, fm1, corr);
  }

  k_topk<<<NPIX / 4, 256, 0, stream>>>(corr, mds, out);
}

// Round 14
// 127.202 us; speedup vs baseline: 1.0870x; 1.0870x over previous
//
#include <hip/hip_runtime.h>
#include <hip/hip_bf16.h>
#include <math.h>

#define H 120
#define W 216
#define C 256
#define NPIX (H*W)
#define PATCH 13
#define PP 169
#define RAD 6
#define TOPKN 36
#define OBJ 11
#define MD 4
#define CW 344   // padded corr row stride (338 -> 344)

typedef unsigned short ushort;
typedef unsigned int   uint;
typedef __attribute__((ext_vector_type(8))) __bf16 bf16x8;
typedef __attribute__((ext_vector_type(4))) float   f32x4;

#define PLANE_B ((size_t)NPIX * 512)   // bytes per hi/lo plane of a transposed tensor

// corr tile geometry
#define YT 8                    // y rows per block
#define RT 20                   // staged fm rows = YT + 12
#define XT 16                   // x cols per block (one M tile)
#define UW 32                   // u window = XT + 16
#define PXS 128                 // staged px stride: 2 planes x 64B, XOR-swizzled reads
#define ROWS (UW * PXS)         // 4096 B per staged row
#define BUFB (RT * ROWS)        // 81920 B per buffer
#define NXT 14                  // ceil(216/16)
#define NYT 15                  // 120/8
#define NWG2 (NXT * NYT)        // 210 blocks (both frames per block)

__device__ inline ushort f2bf_rne(float x) {
  uint u = __float_as_uint(x);
  uint r = (u + 0x7FFFu + ((u >> 16) & 1u)) >> 16;
  return (ushort)r;
}
__device__ inline float bf2f(ushort h) { return __uint_as_float(((uint)h) << 16); }

// ---------------- kernel 0: transpose + hi/lo bf16 split ----------------
__global__ __launch_bounds__(256) void k_prep(const float* __restrict__ fq,
                      const float* __restrict__ fm0, const float* __restrict__ fm1,
                      char* fqt, char* fm0t, char* fm1t) {
  const float* src = (blockIdx.z == 0) ? fq : (blockIdx.z == 1) ? fm0 : fm1;
  char* dst = (blockIdx.z == 0) ? fqt : (blockIdx.z == 1) ? fm0t : fm1t;

  const int p0 = blockIdx.x * 64;
  const int c0 = blockIdx.y * 64;
  const int tid = threadIdx.x;

  __shared__ float ts[64 * 65];
  {
    int p = tid & 63, cl = tid >> 6;
    #pragma unroll
    for (int jj = 0; jj < 16; ++jj) {
      int c = 4 * jj + cl;
      ts[c * 65 + p] = src[(size_t)(c0 + c) * NPIX + p0 + p];
    }
  }
  __syncthreads();
  {
    int pl = tid >> 2, sub = tid & 3;
    ushort hb[16], lb[16];
    #pragma unroll
    for (int i = 0; i < 16; ++i) {
      float x = ts[(sub * 16 + i) * 65 + pl];
      ushort h = f2bf_rne(x);
      hb[i] = h;
      lb[i] = f2bf_rne(x - bf2f(h));
    }
    size_t off = (size_t)(p0 + pl) * 512 + (size_t)c0 * 2 + sub * 32;
    *(uint4*)(dst + off)            = ((uint4*)hb)[0];
    *(uint4*)(dst + off + 16)       = ((uint4*)hb)[1];
    *(uint4*)(dst + PLANE_B + off)      = ((uint4*)lb)[0];
    *(uint4*)(dst + PLANE_B + off + 16) = ((uint4*)lb)[1];
  }
}

// ---------------- kernel 1: mask downsample (::4,::4) ----------------
__global__ void k_downsample(const float* __restrict__ m0, const float* __restrict__ m1,
                             float* __restrict__ mds) {
  int i = blockIdx.x * 256 + threadIdx.x;
  const int total = 2 * OBJ * NPIX;
  if (i >= total) return;
  int fo = i / NPIX;
  int pix = i - fo * NPIX;
  int f = fo / OBJ, o = fo - f * OBJ;
  int y = pix / W, x = pix - y * W;
  const float* src = f ? m1 : m0;
  mds[i] = src[(size_t)o * (H*MD) * (W*MD) + (size_t)(MD*y) * (W*MD) + MD*x];
}

// ---------------- kernel 2 (MFMA, R12 light waves + both frames per block) ----------------
// R12 structure (wave = (y, nt), 16 waves, 4 waves/SIMD) but each block runs BOTH frames
// sequentially (16 kc steps, same dbuf cadence) -> 210 blocks = one grid round, no tail.
// Band extract + acc reset between frames. Per-acc MFMA chain identical to R12
// (kc asc x [AhBh, AhBl, AlBh]) -> corr bit-identical.
__global__ __launch_bounds__(1024, 4) void k_corr_mfma(const char* __restrict__ fqt,
                        const char* __restrict__ fm0t, const char* __restrict__ fm1t,
                        float* __restrict__ corr) {
  // bijective XCD swizzle: 210 = 8*26 + 2
  int b = blockIdx.x;
  int xcd = b & 7, idx = b >> 3;
  int wgid = (xcd < 2) ? xcd * 27 + idx : 54 + (xcd - 2) * 26 + idx;
  int yt   = wgid % NYT;
  int xt   = wgid / NYT;

  const int y0 = yt * YT;
  const int X0 = xt * XT;
  const int tid  = threadIdx.x;
  const int wv   = tid >> 6;           // wave id 0..15
  const int wyy  = wv >> 1;            // y offset in tile 0..7
  const int nt   = wv & 1;             // u group
  const int lane = tid & 63;
  const int l15  = lane & 15, l4 = lane >> 4;
  const int y    = y0 + wyy;

  __shared__ __align__(16) char bsm[2 * BUFB];   // 163840 B

  // ---- staging sources: 5120 granules = 1024 threads x 5; linear dest, inverse-swz source
  uint soff[5];
  uint ldst;   // LDS dest base for this thread's granules (stride 16384)
  {
    // descriptors are frame-relative (uint offsets < 53 MB)
  }
  #pragma unroll
  for (int i = 0; i < 5; ++i) {
    int gdest = wv * 64 + lane + 1024 * i;
    int ri  = gdest >> 8;          // 0..19
    int rem = gdest & 255;
    int px  = rem >> 3;            // 0..31
    int pqp = rem & 7;
    int pqs = pqp ^ (px & 7);      // source (p,q) granule (rule #21 inverse swizzle)
    int p   = pqs >> 2, q = pqs & 3;
    int r = y0 - 6 + ri;  r = (r < 0) ? 0 : (r >= H ? H - 1 : r);
    int u = X0 - 8 + px;  u = (u < 0) ? 0 : (u >= W ? W - 1 : u);
    soff[i] = (uint)((size_t)p * PLANE_B + (size_t)(r * W + u) * 512 + q * 16);
  }
  ldst = (uint)(wv * 1024 + lane * 16);

  // A base (x = X0 + l15, octet l4)
  int xA = X0 + l15;
  const char* pa = fqt + (size_t)(y * W + (xA < W ? xA : W - 1)) * 512 + l4 * 16;

  // B read offsets (within a staged row), swizzled to match the source permutation
  const int pxn = 16 * nt + l15;
  const uint sw  = (uint)((l15 & 7) << 4);
  const uint bh_off = (uint)((pxn * PXS +      l4 * 16) ^ sw);
  const uint bl_off = (uint)((pxn * PXS + 64 + l4 * 16) ^ sw);

  int u0 = X0 + 16 * nt + l15 - 8;
  bool uok = (u0 >= 0) && (u0 < W);

  f32x4 acc[13];
  #pragma unroll
  for (int di = 0; di < 13; ++di) acc[di] = (f32x4){0.f, 0.f, 0.f, 0.f};

  // async stage: 5 x global_load_lds(16B) per thread into buf from frame fb, chunk kn
  auto STAGE = [&](int buf, const char* fb, int kn) {
    #pragma unroll
    for (int i = 0; i < 5; ++i)
      __builtin_amdgcn_global_load_lds(
        (const __attribute__((address_space(1))) void*)(fb + soff[i] + kn * 64),
        (__attribute__((address_space(3))) void*)(bsm + buf * BUFB + ldst + i * 16384),
        16, 0, 0);
  };

  STAGE(0, fm0t, 0);
  uint4 aCh = *(const uint4*)(pa);
  uint4 aCl = *(const uint4*)(pa + PLANE_B);
  uint4 aNh, aNl;
  __syncthreads();   // buf0 ready

  #pragma unroll
  for (int fi = 0; fi < 2; ++fi) {
    #pragma unroll
    for (int kc = 0; kc < 8; ++kc) {
      int t = fi * 8 + kc;
      if (t < 15) {
        const char* sfb = (t < 7) ? fm0t : fm1t;   // frame of step t+1
        int kn = (kc + 1) & 7;
        STAGE((kc + 1) & 1, sfb, kn);              // flies under this step's compute
        aNh = *(const uint4*)(pa + kn * 64);
        aNl = *(const uint4*)(pa + PLANE_B + kn * 64);
      }
      const char* bb = bsm + (kc & 1) * BUFB;
      bf16x8 Ahv = __builtin_bit_cast(bf16x8, aCh);
      bf16x8 Alv = __builtin_bit_cast(bf16x8, aCl);

      #pragma unroll
      for (int di = 0; di < 13; ++di) {
        int rr = y + di - RAD;
        if (rr >= 0 && rr < H) {                   // wave-uniform
          const char* rb = bb + (wyy + di) * ROWS;
          bf16x8 Bhv = *(const bf16x8*)(rb + bh_off);
          bf16x8 Blv = *(const bf16x8*)(rb + bl_off);
          acc[di] = __builtin_amdgcn_mfma_f32_16x16x32_bf16(Ahv, Bhv, acc[di], 0, 0, 0);
          acc[di] = __builtin_amdgcn_mfma_f32_16x16x32_bf16(Ahv, Blv, acc[di], 0, 0, 0);
          acc[di] = __builtin_amdgcn_mfma_f32_16x16x32_bf16(Alv, Bhv, acc[di], 0, 0, 0);
        }
      }
      aCh = aNh; aCl = aNl;                        // static rotate
      __syncthreads();                             // vmcnt drain + barrier
    }

    // ---- band extraction for frame fi, then reset acc for the next frame ----
    float* cb = corr + (size_t)(y * W) * CW + fi * PP;
    #pragma unroll
    for (int di = 0; di < 13; ++di) {
      #pragma unroll
      for (int j = 0; j < 4; ++j) {
        int m  = l4 * 4 + j;
        int x  = X0 + m;
        int dj = 16 * nt + l15 - m - 2;
        if (x < W && dj >= 0 && dj < PATCH)
          cb[(size_t)x * CW + di * PATCH + dj] = uok ? acc[di][j] * 0.0625f : 0.f;
      }
      acc[di] = (f32x4){0.f, 0.f, 0.f, 0.f};
    }
  }
}

// ---------------- kernel 2 fallback (VALU, R2-validated) ----------------
__global__ __launch_bounds__(64) void k_corr_valu(const float* __restrict__ fq,
                       const float* __restrict__ fm0, const float* __restrict__ fm1,
                       float* __restrict__ corr) {
  int b = blockIdx.x;
  int lb = (b & 7) * 390 + (b >> 3);
  int y   = lb / 26;
  int r26 = lb - y * 26;
  int f   = r26 / 13;
  int di  = r26 - f * 13;
  const int tid = threadIdx.x;
  const int xg  = tid;
  const int r   = y + di - RAD;

  float* corr_base = corr + (size_t)(y * W) * CW + (f * PP + di * PATCH);

  if (r < 0 || r >= H) {
    if (xg < 54) {
      float* cp = corr_base + (size_t)(4 * xg) * CW;
      #pragma unroll
      for (int sub = 0; sub < 4; ++sub) {
        #pragma unroll
        for (int dj = 0; dj < PATCH; ++dj) cp[(size_t)sub * CW + dj] = 0.f;
      }
    }
    return;
  }

  const float* fm = f ? fm1 : fm0;
  __shared__ float fm_s[4 * 232];

  const float* pf[4];
  int  ldsoff[4];
  bool sval[4], mval[4];
  #pragma unroll
  for (int s = 0; s < 4; ++s) {
    int i = tid + 64 * s;
    sval[s] = (i < 232);
    int ii = sval[s] ? i : 0;
    int ch = ii / 58;
    int m  = ii - ch * 58;
    int x  = 4 * m - 8;
    mval[s] = sval[s] && (m >= 2) && (m <= 55);
    ldsoff[s] = ch * 232 + 4 * m;
    pf[s] = fm + (size_t)ch * NPIX + (size_t)r * W + (mval[s] ? x : 0);
  }

  const float* pq = fq + (size_t)y * W + 4 * ((xg < 54) ? xg : 0);

  float4 acc[PATCH];
  #pragma unroll
  for (int d = 0; d < PATCH; ++d) acc[d] = make_float4(0.f, 0.f, 0.f, 0.f);

  for (int c0 = 0; c0 < C; c0 += 4) {
    #pragma unroll
    for (int s = 0; s < 4; ++s) {
      if (sval[s]) {
        float4 v = make_float4(0.f, 0.f, 0.f, 0.f);
        if (mval[s]) v = *(const float4*)(pf[s]);
        *(float4*)&fm_s[ldsoff[s]] = v;
        pf[s] += 4 * (size_t)NPIX;
      }
    }
    __syncthreads();
    if (xg < 54) {
      #pragma unroll
      for (int ch = 0; ch < 4; ++ch) {
        float4 q4 = *(const float4*)(pq + (size_t)ch * NPIX);
        float rv[20];
        #pragma unroll
        for (int qq = 0; qq < 5; ++qq) {
          float4 t4 = *(const float4*)&fm_s[ch * 232 + 4 * xg + 4 * qq];
          rv[4*qq+0] = t4.x; rv[4*qq+1] = t4.y; rv[4*qq+2] = t4.z; rv[4*qq+3] = t4.w;
        }
        #pragma unroll
        for (int dj = 0; dj < PATCH; ++dj) {
          acc[dj].x += q4.x * rv[dj + 2];
          acc[dj].y += q4.y * rv[dj + 3];
          acc[dj].z += q4.z * rv[dj + 4];
          acc[dj].w += q4.w * rv[dj + 5];
        }
      }
      pq += 4 * (size_t)NPIX;
    }
    __syncthreads();
  }

  if (xg < 54) {
    float* cp = corr_base + (size_t)(4 * xg) * CW;
    #pragma unroll
    for (int dj = 0; dj < PATCH; ++dj) {
      cp[dj]                  = acc[dj].x * 0.0625f;
      cp[(size_t)1 * CW + dj] = acc[dj].y * 0.0625f;
      cp[(size_t)2 * CW + dj] = acc[dj].z * 0.0625f;
      cp[(size_t)3 * CW + dj] = acc[dj].w * 0.0625f;
    }
  }
}

// ---------------- kernel 3: per-pixel top-36, two-level ballot rank select ----------------
// Phase 1: 16-iter binary search on TOP-16 bits of the monotone key -> bucket k16.
// If bucket-tie count e == need (distinct-values common case): accept = (ui>>16 >= k16),
// set-exact vs jax.lax.top_k, no low-bit search, no serial mbcnt loop.
// Else (border-pixel zero ties etc.): 16-iter low-bit refine + mbcnt index tie-break.
// Softmax shift-invariant -> tf = bucket lower bound is exact up to fp rounding.
__global__ __launch_bounds__(256) void k_topk(const float* __restrict__ corr,
                       const float* __restrict__ mds, float* __restrict__ out) {
  int wid = (blockIdx.x * 256 + threadIdx.x) >> 6;
  int lane = threadIdx.x & 63;
  if (wid >= NPIX) return;
  const float* cr = corr + (size_t)wid * CW;

  float v[6]; uint ui[6];
  #pragma unroll
  for (int s = 0; s < 6; ++s) {
    int idx = lane + 64 * s;
    bool ok = idx < 2 * PP;
    float f = ok ? cr[idx] : 0.f;
    v[s] = f;
    uint bb = __float_as_uint(f);
    uint u = bb ^ (uint)(((int)bb >> 31) | 0x80000000);
    ui[s] = ok ? u : 0u;     // padding: ui=0, never reaches any real bucket (k16>0 always)
  }

  // ---- phase 1: top-16-bit bucket search ----
  uint lo = 0u, hi = 0xFFFFu;
  for (int it = 0; it < 16; ++it) {
    uint mid = (lo + hi) >> 1;
    int c = 0;
    #pragma unroll
    for (int s = 0; s < 6; ++s)
      c += __popcll(__ballot((ui[s] >> 16) > mid));
    if (c <= 35) hi = mid; else lo = mid + 1;
  }
  const uint k16 = lo;

  int g = 0, e = 0;
  #pragma unroll
  for (int s = 0; s < 6; ++s) {
    g += __popcll(__ballot((ui[s] >> 16) > k16));
    e += __popcll(__ballot((ui[s] >> 16) == k16));
  }
  const int need = 36 - g;

  float w[6];
  float zp = 0.f;

  if (e == need) {
    // ---- simple path: accept the whole bucket ----
    uint x0 = k16 << 16;
    uint tb = (x0 & 0x80000000u) ? (x0 ^ 0x80000000u) : ~x0;
    const float tf = __uint_as_float(tb);
    #pragma unroll
    for (int s = 0; s < 6; ++s) {
      bool a = (ui[s] >> 16) >= k16;
      w[s] = a ? __expf(v[s] - tf) : 0.f;
      zp += w[s];
    }
  } else {
    // ---- refine path: 16-iter low-bit search within the bucket + index tie-break ----
    uint l2 = k16 << 16, h2 = (k16 << 16) | 0xFFFFu;
    for (int it = 0; it < 16; ++it) {
      uint mid = l2 + ((h2 - l2) >> 1);
      int c = 0;
      #pragma unroll
      for (int s = 0; s < 6; ++s)
        c += __popcll(__ballot(ui[s] > mid));
      if (c <= 35) h2 = mid; else l2 = mid + 1;
    }
    const uint x0 = l2;
    int cgt = 0;
    #pragma unroll
    for (int s = 0; s < 6; ++s) cgt += __popcll(__ballot(ui[s] > x0));
    const int needT = 36 - cgt;
    uint tb = (x0 & 0x80000000u) ? (x0 ^ 0x80000000u) : ~x0;
    const float tf = __uint_as_float(tb);
    int prior = 0;
    #pragma unroll
    for (int s = 0; s < 6; ++s) {
      unsigned long long tie = __ballot(ui[s] == x0);
      uint below = __builtin_amdgcn_mbcnt_hi((uint)(tie >> 32),
                    __builtin_amdgcn_mbcnt_lo((uint)tie, 0u));
      bool a = (ui[s] > x0) || ((ui[s] == x0) && ((prior + (int)below) < needT));
      prior += __popcll(tie);
      w[s] = a ? __expf(v[s] - tf) : 0.f;
      zp += w[s];
    }
  }

  float Z = zp;
  #pragma unroll
  for (int off = 32; off >= 1; off >>= 1) Z += __shfl_xor(Z, off, 64);

  int y = wid / W, x = wid - (wid / W) * W;
  float no[OBJ];
  #pragma unroll
  for (int o = 0; o < OBJ; ++o) no[o] = 0.f;
  #pragma unroll
  for (int s = 0; s < 6; ++s) {
    if (w[s] > 0.f) {
      int idx = lane + 64 * s;
      int ff = idx >= PP;
      int r = idx - ff * PP;
      int di = r / PATCH, dj = r - (r / PATCH) * PATCH;
      int yy = y + di - RAD, xx = x + dj - RAD;
      if (yy >= 0 && yy < H && xx >= 0 && xx < W) {
        const float* mb = mds + ((size_t)ff * OBJ) * NPIX + yy * W + xx;
        #pragma unroll
        for (int o = 0; o < OBJ; ++o) no[o] += w[s] * mb[(size_t)o * NPIX];
      }
    }
  }
  float inv = 1.f / Z;
  #pragma unroll
  for (int o = 0; o < OBJ; ++o) {
    float pr = no[o];
    #pragma unroll
    for (int off = 32; off >= 1; off >>= 1) pr += __shfl_xor(pr, off, 64);
    if (lane == 0) out[(size_t)o * NPIX + wid] = pr * inv;
  }
}

extern "C" void kernel_launch(void* const* d_in, const int* in_sizes, int n_in,
                              void* d_out, int out_size, void* d_ws, size_t ws_size,
                              hipStream_t stream) {
  const float* fq  = (const float*)d_in[0];
  const float* fm0 = (const float*)d_in[1];
  const float* fm1 = (const float*)d_in[2];
  const float* m0  = (const float*)d_in[3];
  const float* m1  = (const float*)d_in[4];
  float* out = (float*)d_out;

  char* ws = (char*)d_ws;
  size_t off = 0;
  auto alloc = [&](size_t sz) { size_t o = off; off = (off + sz + 1023) & ~(size_t)1023; return o; };

  size_t mds_o  = alloc((size_t)2 * OBJ * NPIX * sizeof(float));
  size_t corr_o = alloc((size_t)NPIX * CW * sizeof(float));
  size_t fqt_o  = alloc(2 * PLANE_B);
  size_t fm0t_o = alloc(2 * PLANE_B);
  size_t fm1t_o = alloc(2 * PLANE_B);
  size_t needed = off;

  float* mds  = (float*)(ws + mds_o);
  float* corr = (float*)(ws + corr_o);

  k_downsample<<<(2 * OBJ * NPIX + 255) / 256, 256, 0, stream>>>(m0, m1, mds);

  if (ws_size >= needed) {
    char* fqt  = ws + fqt_o;
    char* fm0t = ws + fm0t_o;
    char* fm1t = ws + fm1t_o;
    dim3 gp(405, 4, 3);
    k_prep<<<gp, 256, 0, stream>>>(fq, fm0, fm1, fqt, fm0t, fm1t);
    k_corr_mfma<<<NWG2, 1024, 0, stream>>>(fqt, fm0t, fm1t, corr);
  } else {
    k_corr_valu<<<120 * 26, 64, 0, stream>>>(fq, fm0, fm1, corr);
  }

  k_topk<<<NPIX / 4, 256, 0, stream>>>(corr, mds, out);
}